// Round 14
// baseline (110.719 us; speedup 1.0000x reference)
//
#include <hip/hip_runtime.h>

#define N_SERIES 1024
#define N_TIME 600
#define INPUT_SIZE 168
#define OUTPUT_SIZE 24
#define N_S 4
#define SEAS 24
#define N_WINDOWS (N_TIME - INPUT_SIZE - OUTPUT_SIZE + 1) /* 409 */
#define SEAS_LEN (N_TIME + SEAS)                          /* 624 */

#define INS_ELEMS (N_WINDOWS * N_SERIES * (INPUT_SIZE + N_S)) /* 72,036,352 */
#define OUTS_ELEMS (N_WINDOWS * N_SERIES * OUTPUT_SIZE)       /* 10,051,584 */
#define LEV_ELEMS (N_SERIES * N_TIME)

#define T 512
#define NBLK 256 /* 4 series per block */

#define OUTS_TASKS (N_WINDOWS * 24)  /* 9,816 f4 per block */
#define INS_TASKS (N_WINDOWS * 172)  /* 70,348 f4 per block */

typedef float f4 __attribute__((ext_vector_type(4)));

// ---------------------------------------------------------------------------
// ONE kernel. Block b owns series [4b, 4b+4) end-to-end:
//   Phase A: wave0 lanes 0-3 scan the 4 series into LDS (q1, lev raw, seas).
//            tq/lv use mod-4 layout [sl][t&3][t>>2] so phase-B2's windowed
//            reads (t = w + 4*e4 + j) are stride-1 across lanes (bank-clean).
//            Waves 1-7 SIMULTANEOUSLY write the block's outsample slice
//            (depends only on y) — hides the scan bubble.
//   B1: all 512 threads: llv = log(lv), tq = log(tq) in LDS; write levels +
//       seas1 to global (coalesced f4).
//   B2: all 512 threads: insample slice from LDS, dense NT f4 stores
//       (per (block,w) run = 172 f4 = exactly 43 aligned cache lines).
// No workspace, no inter-kernel dependencies, no redundant work.
// ---------------------------------------------------------------------------
__global__ __launch_bounds__(T) void fused_kernel(
    const float* __restrict__ y, const float* __restrict__ s_matrix,
    const float* __restrict__ embeds, const int* __restrict__ idxs,
    float* __restrict__ out)
{
    __shared__ __align__(16) float tq[4][4][152];  // q1 -> log(q1)
    __shared__ __align__(16) float lv[4][4][152];  // levels (raw)
    __shared__ __align__(16) float llv[4][4][152]; // log(levels)
    __shared__ __align__(16) float sea[4][SEAS_LEN];
    __shared__ f4 sml[4];

    float* out_ins  = out;
    float* out_outs = out + INS_ELEMS;
    float* out_lev  = out + INS_ELEMS + OUTS_ELEMS;
    float* out_seas = out_lev + LEV_ELEMS;

    const int tid = threadIdx.x;
    const int s0 = blockIdx.x * 4;

    // ---------------- phase A ----------------
    if (tid < 64) {
        if (tid < 4) {
            const int s = s0 + tid;
            const int row = idxs[s];
            const float* e = embeds + row * (2 + SEAS);
            const float lev_sms = 1.0f / (1.0f + __expf(-e[0]));
            const float seas_sms = 1.0f / (1.0f + __expf(-e[1]));
            const float oml = 1.0f - lev_sms, oms = 1.0f - seas_sms;
            const f4* yv4 = (const f4*)(y + s * N_TIME); // 2400B rows: aligned

            f4 cur[6], nxt[6];
#pragma unroll
            for (int i = 0; i < 6; ++i) cur[i] = yv4[i];

            float sb[SEAS];
#pragma unroll
            for (int j = 0; j < SEAS; ++j) {
                float v = __expf(e[2 + j]);
                sb[j] = v;
                sea[tid][j] = v;
            }
            sea[tid][SEAS] = sb[0]; // rolled init_seas[0]

            float lev = __fdividef(cur[0].x, sb[0]);
            lv[tid][0][0] = lev;
            tq[tid][0][0] = lev; // q1(t=0) == y0/s0 == lev0

            // chunk 0: t = 1..23 (ring index = t)
#pragma unroll
            for (int i = 0; i < 6; ++i) nxt[i] = yv4[6 + i];
#pragma unroll
            for (int j = 1; j < 24; ++j) {
                float yt = cur[j >> 2][j & 3];
                float st = sb[j];
                float q1 = __fdividef(yt, st);
                float nl = lev_sms * q1 + oml * lev;
                float ns = seas_sms * __fdividef(yt, nl) + oms * st;
                lev = nl;
                sb[j] = ns;
                lv[tid][j & 3][j >> 2] = nl;
                tq[tid][j & 3][j >> 2] = q1;
                sea[tid][j + SEAS] = ns;
            }
#pragma unroll
            for (int i = 0; i < 6; ++i) cur[i] = nxt[i];

            // chunks c = 1..24: t = 24c + j, ring index = j
#pragma unroll 1
            for (int c = 1; c < 25; ++c) {
                const int t0 = 24 * c;
                if (c < 24) {
                    const f4* p = (const f4*)(y + s * N_TIME + 24 * (c + 1));
#pragma unroll
                    for (int i = 0; i < 6; ++i) nxt[i] = p[i];
                }
#pragma unroll
                for (int j = 0; j < 24; ++j) {
                    const int t = t0 + j;
                    float yt = cur[j >> 2][j & 3];
                    float st = sb[j];
                    float q1 = __fdividef(yt, st);
                    float nl = lev_sms * q1 + oml * lev;
                    float ns = seas_sms * __fdividef(yt, nl) + oms * st;
                    lev = nl;
                    sb[j] = ns;
                    lv[tid][t & 3][t >> 2] = nl;
                    tq[tid][t & 3][t >> 2] = q1;
                    sea[tid][t + SEAS] = ns;
                }
#pragma unroll
                for (int i = 0; i < 6; ++i) cur[i] = nxt[i];
            }
            sml[tid] = *((const f4*)s_matrix + s);
        }
    } else {
        // waves 1-7: outsample slice (y-only), hidden under the scan
        for (int i = tid - 64; i < OUTS_TASKS; i += T - 64) {
            int w = i / 24;
            int r = i - 24 * w;
            int sl = r / 6;
            int j4 = r - 6 * sl;
            const float* yp = y + (s0 + sl) * N_TIME + w + INPUT_SIZE + 4 * j4;
            f4 v = {yp[0], yp[1], yp[2], yp[3]};
            __builtin_nontemporal_store(
                v, (f4*)out_outs + (w * (N_SERIES * 6) + (s0 + sl) * 6 + j4));
        }
    }
    __syncthreads();

    // ---------------- phase B1: logs + levels/seas global writes ----------
    for (int i = tid; i < 2400; i += T) {
        int sl = i / 600;
        int t = i - 600 * sl;
        llv[sl][t & 3][t >> 2] = __logf(lv[sl][t & 3][t >> 2]);
        tq[sl][t & 3][t >> 2] = __logf(tq[sl][t & 3][t >> 2]);
    }
    for (int i = tid; i < 600; i += T) { // levels: 4 sl x 150 f4
        int sl = i / 150;
        int c = i - 150 * sl;
        f4 v = {lv[sl][0][c], lv[sl][1][c], lv[sl][2][c], lv[sl][3][c]};
        *((f4*)(out_lev + (s0 + sl) * N_TIME) + c) = v;
    }
    for (int i = tid; i < 624; i += T) { // seas1: 4 sl x 156 f4
        int sl = i / 156;
        int c = i - 156 * sl;
        *((f4*)(out_seas + (s0 + sl) * SEAS_LEN) + c) = *((f4*)&sea[sl][4 * c]);
    }
    __syncthreads();

    // ---------------- phase B2: insample slice -----------------------------
    for (int ql = tid; ql < INS_TASKS; ql += T) {
        int w = ql / 172;
        int slot = ql - 172 * w;
        int sl = slot / 43;
        int e4 = slot - 43 * sl;
        f4 v;
        if (e4 == 42) {
            v = sml[sl];
        } else {
            int te = w + 167;
            float l = llv[sl][te & 3][te >> 2];
            int t0 = w + 4 * e4;
            v.x = tq[sl][(t0 + 0) & 3][(t0 + 0) >> 2] - l;
            v.y = tq[sl][(t0 + 1) & 3][(t0 + 1) >> 2] - l;
            v.z = tq[sl][(t0 + 2) & 3][(t0 + 2) >> 2] - l;
            v.w = tq[sl][(t0 + 3) & 3][(t0 + 3) >> 2] - l;
        }
        __builtin_nontemporal_store(
            v, (f4*)out_ins + (w * (N_SERIES * 43) + (s0 + sl) * 43 + e4));
    }
}

extern "C" void kernel_launch(void* const* d_in, const int* in_sizes, int n_in,
                              void* d_out, int out_size, void* d_ws, size_t ws_size,
                              hipStream_t stream) {
    const float* y      = (const float*)d_in[0];
    const float* sm     = (const float*)d_in[1];
    const float* embeds = (const float*)d_in[2];
    const int*   idxs   = (const int*)d_in[3];
    (void)d_ws; (void)ws_size;

    fused_kernel<<<NBLK, T, 0, stream>>>(y, sm, embeds, idxs, (float*)d_out);
}